// Round 9
// baseline (140.886 us; speedup 1.0000x reference)
//
#include <hip/hip_runtime.h>
#include <math.h>

#define NCLASS 100
#define NSEG 30
#define HBINS (NSEG * NCLASS)    // 3000
#define HIST_BLOCKS 512          // rows/block = 2048 < 65535 -> u16-safe
#define NREP 8                   // fallback replicas
#define CE_BLOCKS 1024
#define F4_PER_ROW 25            // 100 floats = 25 float4, row-aligned
#define ROWS_PER_GRP 16
#define F4_PER_GRP (F4_PER_ROW * ROWS_PER_GRP)   // 400

__device__ __forceinline__ float e4(float4 v) {
    return __expf(v.x) + __expf(v.y) + __expf(v.z) + __expf(v.w);
}

// ---------------------------------------------------------------------------
// Kernel 1: per-segment label histogram only (reads just target+seg = 8 MB).
// priv=1: block-private u16 replica, plain stores (no zeroing needed).
// priv=0: NREP int atomic flush (requires memset'd counts).
// ---------------------------------------------------------------------------
__global__ __launch_bounds__(256) void hist_kernel(
    const int* __restrict__ target,
    const int* __restrict__ seg,
    int N,
    void* __restrict__ dst,
    int priv)
{
    __shared__ int h[HBINS];
    for (int i = threadIdx.x; i < HBINS; i += blockDim.x) h[i] = 0;
    __syncthreads();

    // block b owns int4 indices [b*512, (b+1)*512): fully coalesced
    const int4* t4 = (const int4*)target;
    const int4* s4 = (const int4*)seg;
    const int i4PerBlock = (N / 4) / gridDim.x;                 // 512
    const int base = blockIdx.x * i4PerBlock;
    for (int k = threadIdx.x; k < i4PerBlock; k += blockDim.x) {
        int4 t = t4[base + k];
        int4 s = s4[base + k];
        atomicAdd(&h[s.x * NCLASS + t.x], 1);
        atomicAdd(&h[s.y * NCLASS + t.y], 1);
        atomicAdd(&h[s.z * NCLASS + t.z], 1);
        atomicAdd(&h[s.w * NCLASS + t.w], 1);
    }
    __syncthreads();

    if (priv) {
        unsigned int* my = (unsigned int*)dst + (size_t)blockIdx.x * (HBINS / 2);
        for (int i = threadIdx.x; i < HBINS / 2; i += blockDim.x)
            my[i] = (unsigned int)h[2 * i] | ((unsigned int)h[2 * i + 1] << 16);
    } else {
        int* my = (int*)dst + (size_t)(blockIdx.x & (NREP - 1)) * HBINS;
        for (int i = threadIdx.x; i < HBINS; i += blockDim.x) {
            int c = h[i];
            if (c) atomicAdd(&my[i], c);
        }
    }
}

// ---------------------------------------------------------------------------
// Kernel 2: grid = NSEG+1 blocks.
// Blocks 0..29: sum replicas for segment b, first-max argmax (jnp tie rule:
// packed key (count<<7)|(127-c), max-key == smallest class among ties).
// Block 30: zero the loss accumulator + completion ticket for kernel 3.
// ---------------------------------------------------------------------------
__global__ __launch_bounds__(256) void finalize_kernel(
    const void* __restrict__ counts,
    int priv,
    int* __restrict__ g_mode,
    double* __restrict__ g_loss,
    int* __restrict__ g_ticket)
{
    __shared__ int tot2[2][NCLASS];
    const int b = blockIdx.x;
    if (b < NSEG) {
        const int c    = threadIdx.x & 127;
        const int half = threadIdx.x >> 7;           // 0 or 1
        if (c < NCLASS) {
            int v = 0;
            if (priv) {
                const unsigned short* p = (const unsigned short*)counts
                    + (size_t)half * (HIST_BLOCKS / 2) * HBINS + b * NCLASS + c;
                for (int r = 0; r < HIST_BLOCKS / 2; ++r)
                    v += p[(size_t)r * HBINS];
            } else if (half == 0) {
                #pragma unroll
                for (int r = 0; r < NREP; ++r)
                    v += ((const int*)counts)[r * HBINS + b * NCLASS + c];
            }
            tot2[half][c] = v;
        }
        __syncthreads();
        if (threadIdx.x < 64) {
            int bestKey = -1;
            for (int c2 = threadIdx.x; c2 < NCLASS; c2 += 64) {
                int key = ((tot2[0][c2] + tot2[1][c2]) << 7) | (127 - c2);
                bestKey = max(bestKey, key);
            }
            #pragma unroll
            for (int off = 32; off; off >>= 1)
                bestKey = max(bestKey, __shfl_xor(bestKey, off));
            if (threadIdx.x == 0) g_mode[b] = 127 - (bestKey & 127);
        }
    } else if (threadIdx.x == 0) {
        *g_loss = 0.0;
        *g_ticket = 0;
    }
}

// ---------------------------------------------------------------------------
// Kernel 3: fused CE loss + relabel write (round-4 streaming structure).
// Per group (16 rows = 6400B contiguous): 1024B-coalesced loads, exp partials
// through a per-wave LDS bounce, quad-per-row reduce, L2-hot x[target] gather.
// Relabel (out[1+row] = mode[seg[row]]) rides along with the stream.
// Loss finished in-kernel via last-block ticket.
// ---------------------------------------------------------------------------
__global__ __launch_bounds__(256) void ce_relabel_kernel(
    const float* __restrict__ logits,   // [N, 100]
    const int*   __restrict__ target,   // [N]
    const int*   __restrict__ seg,      // [N]
    int N,
    const int* __restrict__ g_mode,     // [NSEG]
    double* __restrict__ g_loss,
    int*    __restrict__ g_ticket,
    float*  __restrict__ out)           // out[0]=loss, out+1 = relabeled[N]
{
    __shared__ float  part[4][F4_PER_GRP];       // 6.4 KB (per-wave slices)
    __shared__ double lds_loss[4];
    __shared__ float  mode_f[NSEG];

    if (threadIdx.x < NSEG) mode_f[threadIdx.x] = (float)g_mode[threadIdx.x];
    __syncthreads();

    const int lane          = threadIdx.x & 63;
    const int wv            = threadIdx.x >> 6;
    const int sub           = lane & 3;     // quad sub-index (pass 2)
    const int q             = lane >> 2;    // row within group (pass 2)
    const int wavesPerBlock = blockDim.x >> 6;
    const int gwave         = blockIdx.x * wavesPerBlock + wv;
    const int totWaves      = gridDim.x * wavesPerBlock;
    const int ngroups       = N >> 4;       // N % 16 == 0

    double acc = 0.0;

    for (int grp = gwave; grp < ngroups; grp += totWaves) {
        const int row = grp * ROWS_PER_GRP + q;

        const int t = target[row];
        const int s = seg[row];

        // ---- pass 1: sequential 1024B-coalesced loads + exp partials ----
        const float4* g4 = (const float4*)logits + (size_t)grp * F4_PER_GRP;
        float4 f0 = g4[lane        ];
        float4 f1 = g4[lane + 64   ];
        float4 f2 = g4[lane + 128  ];
        float4 f3 = g4[lane + 192  ];
        float4 f4v= g4[lane + 256  ];
        float4 f5 = g4[lane + 320  ];

        part[wv][lane      ] = e4(f0);
        part[wv][lane + 64 ] = e4(f1);
        part[wv][lane + 128] = e4(f2);
        part[wv][lane + 192] = e4(f3);
        part[wv][lane + 256] = e4(f4v);
        part[wv][lane + 320] = e4(f5);
        if (lane < 16) {
            float4 f6 = g4[lane + 384];
            part[wv][lane + 384] = e4(f6);
        }
        // same-wave producer->consumer: lgkmcnt ordering, no barrier needed

        // ---- pass 2: quad-per-row gather of 25 partials ----
        const int base = F4_PER_ROW * q + sub;
        float e = part[wv][base     ] + part[wv][base + 4 ] + part[wv][base + 8 ]
                + part[wv][base + 12] + part[wv][base + 16] + part[wv][base + 20];
        if (sub == 0) e += part[wv][F4_PER_ROW * q + 24];
        e += __shfl_xor(e, 1);
        e += __shfl_xor(e, 2);

        // x[target]: L1/L2-hot gather (this CU just streamed those lines)
        const float xt = logits[(size_t)row * NCLASS + t];

        if (sub == 0) {
            acc += (double)(__logf(e) - xt);
            out[1 + row] = mode_f[s];        // fused relabel (64B/group/wave)
        }
    }

    // full-wave sum of acc (nonzero only on sub==0 lanes)
    #pragma unroll
    for (int off = 32; off; off >>= 1) acc += __shfl_xor(acc, off);
    if (lane == 0) lds_loss[wv] = acc;
    __syncthreads();

    if (threadIdx.x == 0) {
        double b = 0.0;
        for (int w = 0; w < wavesPerBlock; ++w) b += lds_loss[w];
        atomicAdd(g_loss, b);
        __threadfence();
        int done = atomicAdd(g_ticket, 1);
        if (done == (int)gridDim.x - 1) {
            double tot = atomicAdd(g_loss, 0.0);   // coherent read of final sum
            out[0] = (float)(tot / (double)N);
        }
    }
}

// ---------------------------------------------------------------------------
extern "C" void kernel_launch(void* const* d_in, const int* in_sizes, int n_in,
                              void* d_out, int out_size, void* d_ws, size_t ws_size,
                              hipStream_t stream)
{
    const float* logits = (const float*)d_in[0];
    const int*   target = (const int*)d_in[1];
    const int*   seg    = (const int*)d_in[2];
    float* out = (float*)d_out;

    const int N = in_sizes[1];          // N_PIXELS (2^20)

    const size_t priv_counts_bytes = (size_t)HIST_BLOCKS * HBINS * sizeof(unsigned short); // 3.0 MB
    const size_t fb_counts_bytes   = (size_t)NREP * HBINS * sizeof(int);                   // 96 KB

    if (ws_size >= priv_counts_bytes + 256) {
        // atomic-free hist path: no memset dispatch at all
        void*   counts   = d_ws;
        int*    g_mode   = (int*)((char*)d_ws + priv_counts_bytes);
        double* g_loss   = (double*)((char*)d_ws + priv_counts_bytes + 128);
        int*    g_ticket = (int*)((char*)d_ws + priv_counts_bytes + 136);

        hist_kernel<<<HIST_BLOCKS, 256, 0, stream>>>(target, seg, N, counts, 1);
        finalize_kernel<<<NSEG + 1, 256, 0, stream>>>(counts, 1, g_mode, g_loss, g_ticket);
        ce_relabel_kernel<<<CE_BLOCKS, 256, 0, stream>>>(
            logits, target, seg, N, g_mode, g_loss, g_ticket, out);
    } else {
        // fallback: NREP atomic flush (memset'd), same downstream structure
        void*   counts   = d_ws;
        int*    g_mode   = (int*)((char*)d_ws + fb_counts_bytes);
        double* g_loss   = (double*)((char*)d_ws + fb_counts_bytes + 128);
        int*    g_ticket = (int*)((char*)d_ws + fb_counts_bytes + 136);

        hipMemsetAsync(counts, 0, fb_counts_bytes, stream);
        hist_kernel<<<HIST_BLOCKS, 256, 0, stream>>>(target, seg, N, counts, 0);
        finalize_kernel<<<NSEG + 1, 256, 0, stream>>>(counts, 0, g_mode, g_loss, g_ticket);
        ce_relabel_kernel<<<CE_BLOCKS, 256, 0, stream>>>(
            logits, target, seg, N, g_mode, g_loss, g_ticket, out);
    }
}

// Round 10
// 99.476 us; speedup vs baseline: 1.4163x; 1.4163x over previous
//
#include <hip/hip_runtime.h>
#include <math.h>

#define NCLASS 100
#define NSEG 30
#define NREP 8                   // replicated global count arrays (contention)
#define F4_PER_ROW 25            // 100 floats = 25 float4, row-aligned
#define ROWS_PER_GRP 16
#define F4_PER_GRP (F4_PER_ROW * ROWS_PER_GRP)   // 400

__device__ __forceinline__ float e4(float4 v) {
    return __expf(v.x) + __expf(v.y) + __expf(v.z) + __expf(v.w);
}

// select component c (0..3) of a float4 without runtime vector indexing
__device__ __forceinline__ float sel4(float4 f, int c) {
    float lo = (c & 1) ? f.y : f.x;
    float hi = (c & 1) ? f.w : f.z;
    return (c & 2) ? hi : lo;
}

// ---------------------------------------------------------------------------
// Kernel 1: fused CE partial sum + per-segment label histogram.
// Round-7 streaming structure (best: 1024B-coalesced loads + per-wave LDS
// bounce + NREP-8 flush). ONE change: x[target] is no longer re-gathered
// from global; it is extracted from the already-loaded registers.
//   tgt[wv][r]  = target of row r (written by sub==0 lanes)
//   lane owning f4 index m = r*25 + t/4 (unique per row) writes
//   xts[wv][r] = that f4's component (t&3).
// Same-wave DS ordering makes the produce->consume safe without barriers.
// ---------------------------------------------------------------------------
__global__ __launch_bounds__(256) void ce_hist_kernel(
    const float* __restrict__ logits,   // [N, 100]
    const int*   __restrict__ target,   // [N]
    const int*   __restrict__ seg,      // [N]
    int N,
    int*    __restrict__ g_counts,      // [NREP][NSEG*NCLASS]
    double* __restrict__ g_loss)        // [1]
{
    __shared__ int    lds_hist[NSEG * NCLASS];   // 12 KB
    __shared__ float  part[4][F4_PER_GRP];       // 6.4 KB (per-wave slices)
    __shared__ int    tgt[4][ROWS_PER_GRP];      // 256 B
    __shared__ float  xts[4][ROWS_PER_GRP];      // 256 B
    __shared__ double lds_loss[4];

    for (int i = threadIdx.x; i < NSEG * NCLASS; i += blockDim.x) lds_hist[i] = 0;
    __syncthreads();

    const int lane          = threadIdx.x & 63;
    const int wv            = threadIdx.x >> 6;
    const int sub           = lane & 3;     // quad sub-index (pass 2)
    const int q             = lane >> 2;    // row within group (pass 2)
    const int wavesPerBlock = blockDim.x >> 6;
    const int gwave         = blockIdx.x * wavesPerBlock + wv;
    const int totWaves      = gridDim.x * wavesPerBlock;
    const int ngroups       = N >> 4;       // N % 16 == 0

    double acc = 0.0;

    for (int grp = gwave; grp < ngroups; grp += totWaves) {
        const int row = grp * ROWS_PER_GRP + q;

        // ids (64B contiguous; quad lanes share the word)
        const int t = target[row];
        const int s = seg[row];
        if (sub == 0) tgt[wv][q] = t;       // publish row targets to the wave

        // ---- pass 1: sequential 1024B-coalesced loads + exp partials ----
        const float4* g4 = (const float4*)logits + (size_t)grp * F4_PER_GRP;
        float4 f0 = g4[lane        ];
        float4 f1 = g4[lane + 64   ];
        float4 f2 = g4[lane + 128  ];
        float4 f3 = g4[lane + 192  ];
        float4 f4v= g4[lane + 256  ];
        float4 f5 = g4[lane + 320  ];
        float4 f6 = make_float4(0.f, 0.f, 0.f, 0.f);
        if (lane < 16) f6 = g4[lane + 384];

        part[wv][lane      ] = e4(f0);
        part[wv][lane + 64 ] = e4(f1);
        part[wv][lane + 128] = e4(f2);
        part[wv][lane + 192] = e4(f3);
        part[wv][lane + 256] = e4(f4v);
        part[wv][lane + 320] = e4(f5);
        if (lane < 16) part[wv][lane + 384] = e4(f6);

        // ---- x[target] extraction from registers (replaces global gather) --
        // lane owns f4 index m = lane + 64k; row r = m/25, col-slot j = m%25.
        // The owner of (r, tgt[r]) writes the component to xts[wv][r].
        {
            float4 fs[7] = { f0, f1, f2, f3, f4v, f5, f6 };
            #pragma unroll
            for (int k = 0; k < 7; ++k) {
                if (k == 6 && lane >= 16) break;
                const int m  = lane + 64 * k;
                const int r  = m / 25;          // magic-mul, compile-time const 25
                const int j  = m - 25 * r;
                const int tr = tgt[wv][r];
                if ((tr >> 2) == j) xts[wv][r] = sel4(fs[k], tr & 3);
            }
        }

        // ---- pass 2: quad-per-row gather of 25 partials ----
        const int base = F4_PER_ROW * q + sub;
        float e = part[wv][base     ] + part[wv][base + 4 ] + part[wv][base + 8 ]
                + part[wv][base + 12] + part[wv][base + 16] + part[wv][base + 20];
        if (sub == 0) e += part[wv][F4_PER_ROW * q + 24];
        e += __shfl_xor(e, 1);
        e += __shfl_xor(e, 2);

        if (sub == 0) {
            const float xt = xts[wv][q];      // same-wave DS order guarantees value
            acc += (double)(__logf(e) - xt);
            atomicAdd(&lds_hist[s * NCLASS + t], 1);
        }
    }

    // full-wave sum of acc (nonzero only on sub==0 lanes)
    #pragma unroll
    for (int off = 32; off; off >>= 1) acc += __shfl_xor(acc, off);
    if (lane == 0) lds_loss[wv] = acc;
    __syncthreads();                 // also fences LDS hist atomics

    if (threadIdx.x == 0) {
        double b = 0.0;
        for (int w = 0; w < wavesPerBlock; ++w) b += lds_loss[w];
        atomicAdd(g_loss, b);
    }
    int* my_counts = g_counts + (blockIdx.x & (NREP - 1)) * (NSEG * NCLASS);
    for (int i = threadIdx.x; i < NSEG * NCLASS; i += blockDim.x) {
        int c = lds_hist[i];
        if (c) atomicAdd(&my_counts[i], c);
    }
}

// ---------------------------------------------------------------------------
// Kernel 2: parallel per-segment argmax over NREP replicas + loss finalize.
// 8 threads per segment; packed key (count<<7)|(127-c): max-key == first-max
// (jnp.argmax tie rule: equal counts -> smaller class id wins).
// ---------------------------------------------------------------------------
__global__ void finalize_kernel(
    const int* __restrict__ g_counts,
    const double* __restrict__ g_loss,
    int N,
    int* __restrict__ g_mode,
    float* __restrict__ out_loss)
{
    const int t = threadIdx.x;        // 256 threads
    const int s = t >> 3;             // segment
    const int j = t & 7;
    if (s < NSEG) {
        int bestKey = -1;
        for (int c = j; c < NCLASS; c += 8) {
            int v = 0;
            #pragma unroll
            for (int r = 0; r < NREP; ++r)          // independent loads -> ILP
                v += g_counts[r * (NSEG * NCLASS) + s * NCLASS + c];
            int key = (v << 7) | (127 - c);
            bestKey = max(bestKey, key);
        }
        bestKey = max(bestKey, __shfl_xor(bestKey, 1));
        bestKey = max(bestKey, __shfl_xor(bestKey, 2));
        bestKey = max(bestKey, __shfl_xor(bestKey, 4));
        if (j == 0) g_mode[s] = 127 - (bestKey & 127);
    }
    if (t == 0) out_loss[0] = (float)(g_loss[0] / (double)N);
}

// ---------------------------------------------------------------------------
// Kernel 3: relabeled[i] = mode[seg[i]] written as fp32
// ---------------------------------------------------------------------------
__global__ __launch_bounds__(256) void relabel_kernel(
    const int* __restrict__ seg,
    const int* __restrict__ g_mode,
    float* __restrict__ out,
    int N)
{
    __shared__ float mode_f[NSEG];
    for (int i = threadIdx.x; i < NSEG; i += blockDim.x)
        mode_f[i] = (float)g_mode[i];
    __syncthreads();

    int idx    = blockIdx.x * blockDim.x + threadIdx.x;
    int stride = gridDim.x * blockDim.x;
    for (int i = idx; i < N; i += stride)
        out[i] = mode_f[seg[i]];
}

// ---------------------------------------------------------------------------
extern "C" void kernel_launch(void* const* d_in, const int* in_sizes, int n_in,
                              void* d_out, int out_size, void* d_ws, size_t ws_size,
                              hipStream_t stream)
{
    const float* logits = (const float*)d_in[0];
    const int*   target = (const int*)d_in[1];
    const int*   seg    = (const int*)d_in[2];
    float* out = (float*)d_out;

    const int N = in_sizes[1];          // N_PIXELS (2^20, divisible by 16)

    // workspace: [0..7] double loss_sum, [16..] counts[NREP][3000], then mode[30]
    double* g_loss   = (double*)d_ws;
    int*    g_counts = (int*)((char*)d_ws + 16);
    int*    g_mode   = (int*)((char*)d_ws + 16 + (size_t)NREP * NSEG * NCLASS * sizeof(int));

    hipMemsetAsync(d_ws, 0, 16 + (size_t)NREP * NSEG * NCLASS * sizeof(int), stream);

    ce_hist_kernel<<<1024, 256, 0, stream>>>(logits, target, seg, N, g_counts, g_loss);
    finalize_kernel<<<1, 256, 0, stream>>>(g_counts, g_loss, N, g_mode, out);
    relabel_kernel<<<2048, 256, 0, stream>>>(seg, g_mode, out + 1, N);
}